// Round 1
// baseline (1002.180 us; speedup 1.0000x reference)
//
#include <hip/hip_runtime.h>
#include <hip/hip_bf16.h>
#include <stdint.h>

typedef __attribute__((ext_vector_type(8))) short short8;
typedef __attribute__((ext_vector_type(8))) unsigned short ushort8;
typedef __attribute__((ext_vector_type(4))) float f32x4;
typedef __attribute__((ext_vector_type(8))) __bf16 bf16x8;

#define GAS __attribute__((address_space(1)))
#define LAS __attribute__((address_space(3)))

static constexpr int Bn = 16384;   // batch
static constexpr int Hn = 1024;    // hidden
static constexpr int KT = 4096;    // IN + H + CTX (concat K)

__device__ __forceinline__ unsigned short f2bf(float f) {
  unsigned u = __builtin_bit_cast(unsigned, f);
  u = (u + 0x7FFFu + ((u >> 16) & 1u)) >> 16;   // RNE
  return (unsigned short)u;
}

__device__ __forceinline__ float sigm(float x) { return 1.f / (1.f + __expf(-x)); }

// Concat-convert 3 fp32 sources (widths 1024,1024,2048) into bf16 [rows][4096].
__global__ __launch_bounds__(256) void cvt_concat_k(
    const float* __restrict__ s0, const float* __restrict__ s1,
    const float* __restrict__ s2, unsigned short* __restrict__ dst,
    long long n8) {
  long long stride = (long long)gridDim.x * blockDim.x;
  for (long long g = (long long)blockIdx.x * blockDim.x + threadIdx.x; g < n8;
       g += stride) {
    long long row = g >> 9;            // 512 groups of 8 per 4096-wide row
    int cg = (int)(g & 511) << 3;
    const float* src;
    if (cg < 1024)      src = s0 + row * 1024 + cg;
    else if (cg < 2048) src = s1 + row * 1024 + (cg - 1024);
    else                src = s2 + row * 2048 + (cg - 2048);
    float4 f0 = *(const float4*)src;
    float4 f1 = *(const float4*)(src + 4);
    ushort8 o;
    o[0] = f2bf(f0.x); o[1] = f2bf(f0.y); o[2] = f2bf(f0.z); o[3] = f2bf(f0.w);
    o[4] = f2bf(f1.x); o[5] = f2bf(f1.y); o[6] = f2bf(f1.z); o[7] = f2bf(f1.w);
    *(ushort8*)(dst + (g << 3)) = o;
  }
}

// Fused GEMM + LSTM cell. m97 structure: 128x(32 cols x 4 gates) tile, BK=64,
// 4 waves (2 row x 2 col), mfma_f32_16x16x32_bf16, global_load_lds width=16.
// Gate-interleaved N-mapping: wave (wr,wc) frag n == gate n at H-columns
// bcol0 + wc*16 + (lane&15), so all 4 gates for an output element live in one
// thread's accumulators -> fully fused epilogue, no gates round-trip.
__global__ __launch_bounds__(256) void lstm_gemm(
    const unsigned short* __restrict__ X, const unsigned short* __restrict__ Wc,
    const float* __restrict__ bias, const float* __restrict__ c0,
    float* __restrict__ out_c, float* __restrict__ out_h) {
  __shared__ unsigned short As[128 * 64];
  __shared__ unsigned short Bs[128 * 64];

  int bid = blockIdx.x;
  int sbid = (bid & 7) * 512 + (bid >> 3);  // XCD chunked swizzle (4096%8==0)
  int mblk = sbid >> 5, cblk = sbid & 31;   // 32 consecutive share A-panel
  int brow0 = mblk * 128, bcol0 = cblk * 32;

  int tid = threadIdx.x;
  int lane = tid & 63, wid = tid >> 6;
  int wr = wid >> 1, wc = wid & 1;
  int lr = lane >> 3;        // row within an 8-row staged chunk
  int lc = (lane & 7) << 3;  // col (elements) within 64-wide K tile

  f32x4 acc[4][4] = {};

  // Per-lane global rows for the 4 staged chunks this wave owns.
  int arow_l[4], brow_l[4];
#pragma unroll
  for (int q = 0; q < 4; ++q) {
    int r = (wid * 4 + q) * 8 + lr;              // LDS tile row 0..127
    arow_l[q] = brow0 + r;
    int wcp = r >> 6, gg = (r >> 4) & 3, fr = r & 15;
    brow_l[q] = gg * 1024 + bcol0 + wcp * 16 + fr;  // weight row (gate gg)
  }

  for (int k0 = 0; k0 < KT; k0 += 64) {
#pragma unroll
    for (int q = 0; q < 4; ++q) {
      int ci = wid * 4 + q;
      const unsigned short* sa = X + (size_t)arow_l[q] * KT + k0 + lc;
      __builtin_amdgcn_global_load_lds((const GAS unsigned int*)sa,
                                       (LAS unsigned int*)&As[ci * 512], 16, 0, 0);
      const unsigned short* sb = Wc + (size_t)brow_l[q] * KT + k0 + lc;
      __builtin_amdgcn_global_load_lds((const GAS unsigned int*)sb,
                                       (LAS unsigned int*)&Bs[ci * 512], 16, 0, 0);
    }
    __syncthreads();
#pragma unroll
    for (int kk = 0; kk < 2; ++kk) {
      int colo = kk * 32 + (lane >> 4) * 8;  // contiguous-8 K per lane-group
      short8 a[4], b[4];
#pragma unroll
      for (int m = 0; m < 4; ++m)
        a[m] = *(const short8*)&As[(wr * 64 + m * 16 + (lane & 15)) * 64 + colo];
#pragma unroll
      for (int n = 0; n < 4; ++n)
        b[n] = *(const short8*)&Bs[(wc * 64 + n * 16 + (lane & 15)) * 64 + colo];
#pragma unroll
      for (int m = 0; m < 4; ++m) {
#pragma unroll
        for (int n = 0; n < 4; ++n) {
          acc[m][n] = __builtin_amdgcn_mfma_f32_16x16x32_bf16(
              __builtin_bit_cast(bf16x8, a[m]), __builtin_bit_cast(bf16x8, b[n]),
              acc[m][n], 0, 0, 0);
        }
      }
    }
    __syncthreads();
  }

  // Fused LSTM epilogue: acc[m][n][j] = gate n, row brow0+wr*64+m*16+(lane>>4)*4+j,
  // H-column bcol0+wc*16+(lane&15)  (C/D map: col=lane&15, row=(lane>>4)*4+reg).
  int col = bcol0 + wc * 16 + (lane & 15);
  float bi = bias[col], bf = bias[1024 + col];
  float bo = bias[2048 + col], bc = bias[3072 + col];
#pragma unroll
  for (int m = 0; m < 4; ++m) {
    int row0 = brow0 + wr * 64 + m * 16 + ((lane >> 4) << 2);
#pragma unroll
    for (int j = 0; j < 4; ++j) {
      size_t idx = (size_t)(row0 + j) * 1024 + col;
      float i_ = sigm(acc[m][0][j] + bi);
      float f_ = sigm(acc[m][1][j] + bf);
      float o_ = sigm(acc[m][2][j] + bo);
      float ch = tanhf(acc[m][3][j] + bc);
      float cn = i_ * ch + f_ * c0[idx];
      out_c[idx] = cn;
      out_h[idx] = o_ * tanhf(cn);
    }
  }
}

// Emergency fallback if ws_size is too small (also tells us ws_size next round).
__global__ __launch_bounds__(256) void lstm_naive(
    const float* __restrict__ y, const float* __restrict__ ctx,
    const float* __restrict__ c0, const float* __restrict__ h0,
    const float* __restrict__ W, const float* __restrict__ U,
    const float* __restrict__ C, const float* __restrict__ b,
    float* __restrict__ out_c, float* __restrict__ out_h) {
  size_t t = (size_t)blockIdx.x * blockDim.x + threadIdx.x;
  if (t >= (size_t)Bn * Hn) return;
  int row = (int)(t >> 10), col = (int)(t & 1023);
  float g[4];
#pragma unroll
  for (int gg = 0; gg < 4; ++gg) {
    int wrow = gg * 1024 + col;
    float s = b[wrow];
    const float* yr = y + (size_t)row * 1024;
    const float* Wr = W + (size_t)wrow * 1024;
    for (int k = 0; k < 1024; ++k) s += yr[k] * Wr[k];
    const float* hr = h0 + (size_t)row * 1024;
    const float* Ur = U + (size_t)wrow * 1024;
    for (int k = 0; k < 1024; ++k) s += hr[k] * Ur[k];
    const float* cr = ctx + (size_t)row * 2048;
    const float* Cr = C + (size_t)wrow * 2048;
    for (int k = 0; k < 2048; ++k) s += cr[k] * Cr[k];
    g[gg] = s;
  }
  float i_ = sigm(g[0]), f_ = sigm(g[1]), o_ = sigm(g[2]), ch = tanhf(g[3]);
  float cn = i_ * ch + f_ * c0[t];
  out_c[t] = cn;
  out_h[t] = o_ * tanhf(cn);
}

extern "C" void kernel_launch(void* const* d_in, const int* in_sizes, int n_in,
                              void* d_out, int out_size, void* d_ws, size_t ws_size,
                              hipStream_t stream) {
  const float* y   = (const float*)d_in[0];
  const float* ctx = (const float*)d_in[1];
  const float* c0  = (const float*)d_in[2];
  const float* h0  = (const float*)d_in[3];
  const float* W   = (const float*)d_in[4];
  const float* U   = (const float*)d_in[5];
  const float* C   = (const float*)d_in[6];
  const float* b   = (const float*)d_in[7];
  float* out = (float*)d_out;
  float* out_c = out;
  float* out_h = out + (size_t)Bn * Hn;

  const size_t needX = (size_t)Bn * KT * 2;       // 128 MB bf16 activations
  const size_t needW = (size_t)(4 * Hn) * KT * 2; //  32 MB bf16 weights

  if (ws_size >= needX + needW) {
    unsigned short* Xb = (unsigned short*)d_ws;
    unsigned short* Wb = (unsigned short*)((char*)d_ws + needX);
    cvt_concat_k<<<2048, 256, 0, stream>>>(y, h0, ctx, Xb, (long long)Bn * 512);
    cvt_concat_k<<<2048, 256, 0, stream>>>(W, U, C, Wb, (long long)(4 * Hn) * 512);
    lstm_gemm<<<4096, 256, 0, stream>>>(Xb, Wb, b, c0, out_c, out_h);
  } else {
    lstm_naive<<<(Bn * Hn + 255) / 256, 256, 0, stream>>>(y, ctx, c0, h0, W, U, C,
                                                          b, out_c, out_h);
  }
}

// Round 2
// 629.816 us; speedup vs baseline: 1.5912x; 1.5912x over previous
//
#include <hip/hip_runtime.h>
#include <hip/hip_bf16.h>
#include <stdint.h>

typedef __attribute__((ext_vector_type(8))) short short8;
typedef __attribute__((ext_vector_type(8))) unsigned short ushort8;
typedef __attribute__((ext_vector_type(4))) float f32x4;
typedef __attribute__((ext_vector_type(8))) __bf16 bf16x8;

#define GAS __attribute__((address_space(1)))
#define LAS __attribute__((address_space(3)))

static constexpr int Bn = 16384;   // batch
static constexpr int Hn = 1024;    // hidden
static constexpr int KT = 4096;    // IN + H + CTX (concat K)
static constexpr int BM = 256;     // M tile
static constexpr int BK = 64;      // K tile
static constexpr int NT = KT / BK; // 64 K-tiles

#define SBAR()   asm volatile("s_barrier" ::: "memory")
#define LGKM0()  asm volatile("s_waitcnt lgkmcnt(0)" ::: "memory")
#define VMCNT(n) asm volatile("s_waitcnt vmcnt(" #n ")" ::: "memory")

__device__ __forceinline__ unsigned short f2bf(float f) {
  unsigned u = __builtin_bit_cast(unsigned, f);
  u = (u + 0x7FFFu + ((u >> 16) & 1u)) >> 16;   // RNE
  return (unsigned short)u;
}

__device__ __forceinline__ float sigm(float x) { return 1.f / (1.f + __expf(-x)); }

// Concat-convert 3 fp32 sources (widths 1024,1024,2048) into bf16 [rows][4096].
__global__ __launch_bounds__(256) void cvt_concat_k(
    const float* __restrict__ s0, const float* __restrict__ s1,
    const float* __restrict__ s2, unsigned short* __restrict__ dst,
    long long n8) {
  long long stride = (long long)gridDim.x * blockDim.x;
  for (long long g = (long long)blockIdx.x * blockDim.x + threadIdx.x; g < n8;
       g += stride) {
    long long row = g >> 9;
    int cg = (int)(g & 511) << 3;
    const float* src;
    if (cg < 1024)      src = s0 + row * 1024 + cg;
    else if (cg < 2048) src = s1 + row * 1024 + (cg - 1024);
    else                src = s2 + row * 2048 + (cg - 2048);
    float4 f0 = *(const float4*)src;
    float4 f1 = *(const float4*)(src + 4);
    ushort8 o;
    o[0] = f2bf(f0.x); o[1] = f2bf(f0.y); o[2] = f2bf(f0.z); o[3] = f2bf(f0.w);
    o[4] = f2bf(f1.x); o[5] = f2bf(f1.y); o[6] = f2bf(f1.z); o[7] = f2bf(f1.w);
    *(ushort8*)(dst + (g << 3)) = o;
  }
}

// 256x256 deep-pipelined GEMM + fused LSTM cell.
// 8 waves (2M x 4N), BK=64, 4 phases/K-tile, double-buffered 128KB LDS,
// st_16x32 XOR swizzle, counted vmcnt (4 @ph1, 2 @ph3 - never 0 mid-loop),
// setprio around MFMA clusters, XCD-chunked block swizzle.
// Gate-interleaved B mapping: wave wc frag n == gate n at H-col
// hcol0 + wc*16 + (lane&15)  -> all 4 gates in one thread -> fused epilogue.
__global__ __launch_bounds__(512, 2) void lstm_gemm(
    const unsigned short* __restrict__ X, const unsigned short* __restrict__ Wc,
    const float* __restrict__ bias, const float* __restrict__ c0,
    float* __restrict__ out_c, float* __restrict__ out_h) {
  extern __shared__ char smem[];  // 131072 B: [2 bufs][A 32KB | B 32KB]

  int bid = blockIdx.x;
  int swz = (bid & 7) * 128 + (bid >> 3);  // 1024 blocks, 8 XCDs, bijective
  int mblk = swz >> 4, cblk = swz & 15;    // 16 consecutive share A-panel
  int brow0 = mblk * BM;
  int hcol0 = cblk * 64;

  int tid = threadIdx.x;
  int lane = tid & 63, wid = tid >> 6;
  int wr = wid >> 2, wc = wid & 3;  // 2 x 4 wave grid

  const char* Xc = (const char*)X;
  const char* Wcc = (const char*)Wc;

  // ---- staging source offsets (inverse-swizzled global, linear LDS dest) ----
  int rr = tid >> 3;                                        // 0..63
  uint32_t cbyte = (uint32_t)(((tid & 7) * 16) ^ ((rr & 7) << 4));
  uint32_t aoff[2][2], boff[2][2];
#pragma unroll
  for (int half = 0; half < 2; ++half) {
#pragma unroll
    for (int j = 0; j < 2; ++j) {
      int r = half * 128 + j * 64 + rr;                     // tile row 0..255
      aoff[half][j] = (uint32_t)(brow0 + r) * (KT * 2) + cbyte;
      int w = ((r >> 4) & 3) * 1024 + hcol0 + ((r >> 6) << 4) + (r & 15);
      boff[half][j] = (uint32_t)w * (KT * 2) + cbyte;
    }
  }

  // stage one 16KB half-tile (2 x global_load_lds, 8KB per 512-thread issue)
  auto stage_half = [&](int isB, int half, int kt, int bufs) {
#pragma unroll
    for (int j = 0; j < 2; ++j) {
      uint32_t off = (isB ? boff[half][j] : aoff[half][j]) + (uint32_t)kt * 128u;
      const char* src = (isB ? Wcc : Xc) + off;
      char* dst = smem + bufs * 65536 + isB * 32768 + half * 16384 + j * 8192 +
                  wid * 1024;
      __builtin_amdgcn_global_load_lds((const GAS unsigned int*)src,
                                       (LAS unsigned int*)dst, 16, 0, 0);
    }
  };

  // ---- ds_read swizzled byte offsets within a 128B row ----
  int kg = (lane >> 4) << 4;               // 0,16,32,48
  int sw = (lane & 7) << 4;
  int koff0 = (0 + kg) ^ sw;               // k-slice 0
  int koff1 = (64 + kg) ^ sw;              // k-slice 1
  int fr = lane & 15;

  f32x4 acc[8][4] = {};
  short8 bfr[4][2];

  // ---- prologue: stage tile 0 (B-lo,B-hi,A-lo,A-hi) ----
  stage_half(1, 0, 0, 0);
  stage_half(1, 1, 0, 0);
  stage_half(0, 0, 0, 0);
  stage_half(0, 1, 0, 0);
  VMCNT(2);  // B + A-lo landed; A-hi may stay in flight
  SBAR();

  for (int t = 0; t < NT; ++t) {
    int p = t & 1;
    bool last = (t == NT - 1);
#pragma unroll
    for (int q = 0; q < 4; ++q) {
      // B-frags once per tile (8 x ds_read_b128), kept in registers
      if (q == 0) {
        int bb = p * 65536 + 32768 + (wc * 64 + fr) * 128;
#pragma unroll
        for (int n = 0; n < 4; ++n) {
          bfr[n][0] = *(const short8*)(smem + bb + n * 2048 + koff0);
          bfr[n][1] = *(const short8*)(smem + bb + n * 2048 + koff1);
        }
      }
      // A-frags for this phase's 2 M-frags (4 x ds_read_b128)
      int ab = p * 65536 + ((2 * q + wr) * 32 + fr) * 128;
      short8 a0k0 = *(const short8*)(smem + ab + koff0);
      short8 a0k1 = *(const short8*)(smem + ab + koff1);
      short8 a1k0 = *(const short8*)(smem + ab + 2048 + koff0);
      short8 a1k1 = *(const short8*)(smem + ab + 2048 + koff1);

      // prefetch 1 half-tile of tile t+1 into the other buffer
      if (!last) stage_half(q < 2 ? 1 : 0, q & 1, t + 1, p ^ 1);

      SBAR();
      LGKM0();
      __builtin_amdgcn_s_setprio(1);
#pragma unroll
      for (int n = 0; n < 4; ++n) {
        acc[2 * q][n] = __builtin_amdgcn_mfma_f32_16x16x32_bf16(
            __builtin_bit_cast(bf16x8, a0k0), __builtin_bit_cast(bf16x8, bfr[n][0]),
            acc[2 * q][n], 0, 0, 0);
        acc[2 * q][n] = __builtin_amdgcn_mfma_f32_16x16x32_bf16(
            __builtin_bit_cast(bf16x8, a0k1), __builtin_bit_cast(bf16x8, bfr[n][1]),
            acc[2 * q][n], 0, 0, 0);
        acc[2 * q + 1][n] = __builtin_amdgcn_mfma_f32_16x16x32_bf16(
            __builtin_bit_cast(bf16x8, a1k0), __builtin_bit_cast(bf16x8, bfr[n][0]),
            acc[2 * q + 1][n], 0, 0, 0);
        acc[2 * q + 1][n] = __builtin_amdgcn_mfma_f32_16x16x32_bf16(
            __builtin_bit_cast(bf16x8, a1k1), __builtin_bit_cast(bf16x8, bfr[n][1]),
            acc[2 * q + 1][n], 0, 0, 0);
      }
      __builtin_amdgcn_s_setprio(0);

      // counted vmcnt: gate next phases' reads, keep newest loads in flight
      if (q == 1) {
        if (last) { VMCNT(0); } else { VMCNT(4); }
      } else if (q == 3 && !last) {
        VMCNT(2);
      }
      SBAR();
    }
  }

  // ---- fused LSTM epilogue (acc[m][n]: n = gate) ----
  int col = hcol0 + wc * 16 + fr;
  float bi = bias[col], bf_ = bias[1024 + col];
  float bo = bias[2048 + col], bc = bias[3072 + col];
#pragma unroll
  for (int m = 0; m < 8; ++m) {
    int row0 = brow0 + (2 * (m >> 1) + wr) * 32 + (m & 1) * 16 + ((lane >> 4) << 2);
#pragma unroll
    for (int j = 0; j < 4; ++j) {
      size_t idx = (size_t)(row0 + j) * 1024 + col;
      float i_ = sigm(acc[m][0][j] + bi);
      float f_ = sigm(acc[m][1][j] + bf_);
      float o_ = sigm(acc[m][2][j] + bo);
      float ch = tanhf(acc[m][3][j] + bc);
      float cn = i_ * ch + f_ * c0[idx];
      out_c[idx] = cn;
      out_h[idx] = o_ * tanhf(cn);
    }
  }
}

// Fallback if ws too small (not expected; ws >= 160MB confirmed in round 1).
__global__ __launch_bounds__(256) void lstm_naive(
    const float* __restrict__ y, const float* __restrict__ ctx,
    const float* __restrict__ c0, const float* __restrict__ h0,
    const float* __restrict__ W, const float* __restrict__ U,
    const float* __restrict__ C, const float* __restrict__ b,
    float* __restrict__ out_c, float* __restrict__ out_h) {
  size_t t = (size_t)blockIdx.x * blockDim.x + threadIdx.x;
  if (t >= (size_t)Bn * Hn) return;
  int row = (int)(t >> 10), col = (int)(t & 1023);
  float g[4];
#pragma unroll
  for (int gg = 0; gg < 4; ++gg) {
    int wrow = gg * 1024 + col;
    float s = b[wrow];
    const float* yr = y + (size_t)row * 1024;
    const float* Wr = W + (size_t)wrow * 1024;
    for (int k = 0; k < 1024; ++k) s += yr[k] * Wr[k];
    const float* hr = h0 + (size_t)row * 1024;
    const float* Ur = U + (size_t)wrow * 1024;
    for (int k = 0; k < 1024; ++k) s += hr[k] * Ur[k];
    const float* cr = ctx + (size_t)row * 2048;
    const float* Cr = C + (size_t)wrow * 2048;
    for (int k = 0; k < 2048; ++k) s += cr[k] * Cr[k];
    g[gg] = s;
  }
  float i_ = sigm(g[0]), f_ = sigm(g[1]), o_ = sigm(g[2]), ch = tanhf(g[3]);
  float cn = i_ * ch + f_ * c0[t];
  out_c[t] = cn;
  out_h[t] = o_ * tanhf(cn);
}

extern "C" void kernel_launch(void* const* d_in, const int* in_sizes, int n_in,
                              void* d_out, int out_size, void* d_ws, size_t ws_size,
                              hipStream_t stream) {
  const float* y   = (const float*)d_in[0];
  const float* ctx = (const float*)d_in[1];
  const float* c0  = (const float*)d_in[2];
  const float* h0  = (const float*)d_in[3];
  const float* W   = (const float*)d_in[4];
  const float* U   = (const float*)d_in[5];
  const float* C   = (const float*)d_in[6];
  const float* b   = (const float*)d_in[7];
  float* out = (float*)d_out;
  float* out_c = out;
  float* out_h = out + (size_t)Bn * Hn;

  const size_t needX = (size_t)Bn * KT * 2;
  const size_t needW = (size_t)(4 * Hn) * KT * 2;

  if (ws_size >= needX + needW) {
    unsigned short* Xb = (unsigned short*)d_ws;
    unsigned short* Wb = (unsigned short*)((char*)d_ws + needX);
    cvt_concat_k<<<2048, 256, 0, stream>>>(y, h0, ctx, Xb, (long long)Bn * 512);
    cvt_concat_k<<<2048, 256, 0, stream>>>(W, U, C, Wb, (long long)(4 * Hn) * 512);
    (void)hipFuncSetAttribute((const void*)lstm_gemm,
                              hipFuncAttributeMaxDynamicSharedMemorySize, 131072);
    lstm_gemm<<<1024, 512, 131072, stream>>>(Xb, Wb, b, c0, out_c, out_h);
  } else {
    lstm_naive<<<(Bn * Hn + 255) / 256, 256, 0, stream>>>(y, ctx, c0, h0, W, U, C,
                                                          b, out_c, out_h);
  }
}

// Round 3
// 557.240 us; speedup vs baseline: 1.7985x; 1.1302x over previous
//
#include <hip/hip_runtime.h>
#include <hip/hip_bf16.h>
#include <stdint.h>

typedef __attribute__((ext_vector_type(8))) short short8;
typedef __attribute__((ext_vector_type(8))) unsigned short ushort8;
typedef __attribute__((ext_vector_type(4))) float f32x4;
typedef __attribute__((ext_vector_type(8))) __bf16 bf16x8;

#define GAS __attribute__((address_space(1)))
#define LAS __attribute__((address_space(3)))

static constexpr int Bn = 16384;   // batch
static constexpr int Hn = 1024;    // hidden
static constexpr int KT = 4096;    // IN + H + CTX (concat K)
static constexpr int BM = 256;     // M tile
static constexpr int NT = KT / 64; // 64 K-tiles

#define SBAR()   __builtin_amdgcn_s_barrier()
#define VMCNT(n) asm volatile("s_waitcnt vmcnt(" #n ")" ::: "memory")

__device__ __forceinline__ unsigned short f2bf(float f) {
  unsigned u = __builtin_bit_cast(unsigned, f);
  u = (u + 0x7FFFu + ((u >> 16) & 1u)) >> 16;   // RNE
  return (unsigned short)u;
}

__device__ __forceinline__ float fast_sigm(float x) {
  return __builtin_amdgcn_rcpf(1.f + __expf(-x));
}
__device__ __forceinline__ float fast_tanh(float x) {
  // 1 - 2/(exp(2x)+1); exp->inf / ->0 saturate correctly to +/-1
  return 1.f - 2.f * __builtin_amdgcn_rcpf(__expf(2.f * x) + 1.f);
}

// Concat-convert 3 fp32 sources (widths 1024,1024,2048) into bf16 [rows][4096].
__global__ __launch_bounds__(256) void cvt_concat_k(
    const float* __restrict__ s0, const float* __restrict__ s1,
    const float* __restrict__ s2, unsigned short* __restrict__ dst,
    long long n8) {
  long long stride = (long long)gridDim.x * blockDim.x;
  for (long long g = (long long)blockIdx.x * blockDim.x + threadIdx.x; g < n8;
       g += stride) {
    long long row = g >> 9;
    int cg = (int)(g & 511) << 3;
    const float* src;
    if (cg < 1024)      src = s0 + row * 1024 + cg;
    else if (cg < 2048) src = s1 + row * 1024 + (cg - 1024);
    else                src = s2 + row * 2048 + (cg - 2048);
    float4 f0 = *(const float4*)src;
    float4 f1 = *(const float4*)(src + 4);
    ushort8 o;
    o[0] = f2bf(f0.x); o[1] = f2bf(f0.y); o[2] = f2bf(f0.z); o[3] = f2bf(f0.w);
    o[4] = f2bf(f1.x); o[5] = f2bf(f1.y); o[6] = f2bf(f1.z); o[7] = f2bf(f1.w);
    *(ushort8*)(dst + (g << 3)) = o;
  }
}

// 256x256 deep-pipelined GEMM + fused LSTM cell.
// 8 waves (2M x 4N), BK=64, 4 phases/K-tile, double-buffered 128KB LDS,
// st_16x32 XOR swizzle (both-sides), BUILTIN s_barrier (no waitcnt drain),
// deep counted-vmcnt ledger:
//   during tile t, phases 0..3 stage: A-hi(t+1), B-lo(t+2), B-hi(t+2), A-lo(t+2)
//   -> every half-tile has 5-7 phases of flight time before its gate.
//   Gates: VMCNT(10) @ ph1-end (A-hi(t) landed), VMCNT(8) @ ph3-end
//   (B-lo/B-hi/A-lo(t+1) landed). Uniform tail via clamped-source dummy stages.
// Gate-interleaved B mapping keeps all 4 gates in one thread -> fused epilogue.
__global__ __launch_bounds__(512, 2) void lstm_gemm(
    const unsigned short* __restrict__ X, const unsigned short* __restrict__ Wc,
    const float* __restrict__ bias, const float* __restrict__ c0,
    float* __restrict__ out_c, float* __restrict__ out_h) {
  extern __shared__ char smem[];  // 131072 B: [2 bufs][A 32KB | B 32KB]

  int bid = blockIdx.x;
  int swz = (bid & 7) * 128 + (bid >> 3);  // 1024 blocks, 8 XCDs, bijective
  int mblk = swz >> 4, cblk = swz & 15;    // 16 consecutive share A-panel
  int brow0 = mblk * BM;
  int hcol0 = cblk * 64;

  int tid = threadIdx.x;
  int lane = tid & 63, wid = tid >> 6;
  int wr = wid >> 2, wc = wid & 3;  // 2 x 4 wave grid

  const char* Xc = (const char*)X;
  const char* Wcc = (const char*)Wc;

  // ---- staging source offsets (inverse-swizzled global, linear LDS dest) ----
  int rr = tid >> 3;                                        // 0..63
  uint32_t cbyte = (uint32_t)(((tid & 7) * 16) ^ ((rr & 7) << 4));
  uint32_t aoff[2][2], boff[2][2];
#pragma unroll
  for (int half = 0; half < 2; ++half) {
#pragma unroll
    for (int j = 0; j < 2; ++j) {
      int r = half * 128 + j * 64 + rr;                     // tile row 0..255
      aoff[half][j] = (uint32_t)(brow0 + r) * (KT * 2) + cbyte;
      int w = ((r >> 4) & 3) * 1024 + hcol0 + ((r >> 6) << 4) + (r & 15);
      boff[half][j] = (uint32_t)w * (KT * 2) + cbyte;
    }
  }

  // stage one 16KB half-tile for target tile tt (dest slot = tt&1; source
  // clamped to the last real tile so the vmcnt ledger stays uniform).
  auto stage_half = [&](int isB, int half, int tt) {
    int ts = tt < NT ? tt : NT - 1;
    int bufs = tt & 1;
#pragma unroll
    for (int j = 0; j < 2; ++j) {
      uint32_t off = (isB ? boff[half][j] : aoff[half][j]) + (uint32_t)ts * 128u;
      const char* src = (isB ? Wcc : Xc) + off;
      char* dst = smem + bufs * 65536 + isB * 32768 + half * 16384 + j * 8192 +
                  wid * 1024;
      __builtin_amdgcn_global_load_lds((const GAS unsigned int*)src,
                                       (LAS unsigned int*)dst, 16, 0, 0);
    }
  };

  // ---- ds_read swizzled byte offsets within a 128B row ----
  int kg = (lane >> 4) << 4;               // 0,16,32,48
  int sw = (lane & 7) << 4;
  int koff0 = (0 + kg) ^ sw;               // k-slice 0
  int koff1 = (64 + kg) ^ sw;              // k-slice 1
  int fr = lane & 15;

  f32x4 acc[8][4] = {};
  short8 bfr[4][2];

  // ---- prologue: tile0 complete + tile1 minus A-hi (7 half-tiles, 14 loads)
  stage_half(1, 0, 0);
  stage_half(1, 1, 0);
  stage_half(0, 0, 0);
  stage_half(0, 1, 0);
  stage_half(1, 0, 1);
  stage_half(1, 1, 1);
  stage_half(0, 0, 1);
  VMCNT(8);  // B0 + A-lo0 landed; A-hi0 + tile1 halves stay in flight
  SBAR();

  for (int t = 0; t < NT; ++t) {
    int p = t & 1;
#pragma unroll
    for (int q = 0; q < 4; ++q) {
      // B-frags once per tile (8 x ds_read_b128), kept in registers
      if (q == 0) {
        int bb = p * 65536 + 32768 + (wc * 64 + fr) * 128;
#pragma unroll
        for (int n = 0; n < 4; ++n) {
          bfr[n][0] = *(const short8*)(smem + bb + n * 2048 + koff0);
          bfr[n][1] = *(const short8*)(smem + bb + n * 2048 + koff1);
        }
      }
      // A-frags for this phase's 2 M-frags (4 x ds_read_b128)
      int ab = p * 65536 + ((2 * q + wr) * 32 + fr) * 128;
      short8 a0k0 = *(const short8*)(smem + ab + koff0);
      short8 a0k1 = *(const short8*)(smem + ab + koff1);
      short8 a1k0 = *(const short8*)(smem + ab + 2048 + koff0);
      short8 a1k1 = *(const short8*)(smem + ab + 2048 + koff1);

      // deep prefetch: one half-tile per phase
      if (q == 0)      stage_half(0, 1, t + 1);  // A-hi(t+1) -> buf p^1
      else if (q == 1) stage_half(1, 0, t + 2);  // B-lo(t+2) -> buf p (B read done @ph0)
      else if (q == 2) stage_half(1, 1, t + 2);  // B-hi(t+2) -> buf p
      else             stage_half(0, 0, t + 2);  // A-lo(t+2) -> buf p (read @ph0/1)

      SBAR();
      __builtin_amdgcn_s_setprio(1);
#pragma unroll
      for (int n = 0; n < 4; ++n) {
        acc[2 * q][n] = __builtin_amdgcn_mfma_f32_16x16x32_bf16(
            __builtin_bit_cast(bf16x8, a0k0), __builtin_bit_cast(bf16x8, bfr[n][0]),
            acc[2 * q][n], 0, 0, 0);
        acc[2 * q][n] = __builtin_amdgcn_mfma_f32_16x16x32_bf16(
            __builtin_bit_cast(bf16x8, a0k1), __builtin_bit_cast(bf16x8, bfr[n][1]),
            acc[2 * q][n], 0, 0, 0);
        acc[2 * q + 1][n] = __builtin_amdgcn_mfma_f32_16x16x32_bf16(
            __builtin_bit_cast(bf16x8, a1k0), __builtin_bit_cast(bf16x8, bfr[n][0]),
            acc[2 * q + 1][n], 0, 0, 0);
        acc[2 * q + 1][n] = __builtin_amdgcn_mfma_f32_16x16x32_bf16(
            __builtin_bit_cast(bf16x8, a1k1), __builtin_bit_cast(bf16x8, bfr[n][1]),
            acc[2 * q + 1][n], 0, 0, 0);
      }
      __builtin_amdgcn_s_setprio(0);

      // counted vmcnt, once-per-gate, never 0 in the loop:
      //  ph1-end: A-hi(t) issued @ t-1 ph0; 10 loads issued since -> VMCNT(10)
      //  ph3-end: A-lo(t+1) issued @ t-1 ph3; 8 loads issued since -> VMCNT(8)
      if (q == 1) { VMCNT(10); }
      else if (q == 3) { VMCNT(8); }
      SBAR();
    }
  }

  // ---- fused LSTM epilogue (acc[m][n]: n = gate) ----
  int col = hcol0 + wc * 16 + fr;
  float bi = bias[col], bf_ = bias[1024 + col];
  float bo = bias[2048 + col], bc = bias[3072 + col];
#pragma unroll
  for (int m = 0; m < 8; ++m) {
    int row0 = brow0 + (2 * (m >> 1) + wr) * 32 + (m & 1) * 16 + ((lane >> 4) << 2);
#pragma unroll
    for (int j = 0; j < 4; ++j) {
      size_t idx = (size_t)(row0 + j) * 1024 + col;
      float i_ = fast_sigm(acc[m][0][j] + bi);
      float f_ = fast_sigm(acc[m][1][j] + bf_);
      float o_ = fast_sigm(acc[m][2][j] + bo);
      float ch = fast_tanh(acc[m][3][j] + bc);
      float cn = i_ * ch + f_ * c0[idx];
      out_c[idx] = cn;
      out_h[idx] = o_ * fast_tanh(cn);
    }
  }
}

// Fallback if ws too small (not expected; ws >= 160MB confirmed in round 1).
__global__ __launch_bounds__(256) void lstm_naive(
    const float* __restrict__ y, const float* __restrict__ ctx,
    const float* __restrict__ c0, const float* __restrict__ h0,
    const float* __restrict__ W, const float* __restrict__ U,
    const float* __restrict__ C, const float* __restrict__ b,
    float* __restrict__ out_c, float* __restrict__ out_h) {
  size_t t = (size_t)blockIdx.x * blockDim.x + threadIdx.x;
  if (t >= (size_t)Bn * Hn) return;
  int row = (int)(t >> 10), col = (int)(t & 1023);
  float g[4];
#pragma unroll
  for (int gg = 0; gg < 4; ++gg) {
    int wrow = gg * 1024 + col;
    float s = b[wrow];
    const float* yr = y + (size_t)row * 1024;
    const float* Wr = W + (size_t)wrow * 1024;
    for (int k = 0; k < 1024; ++k) s += yr[k] * Wr[k];
    const float* hr = h0 + (size_t)row * 1024;
    const float* Ur = U + (size_t)wrow * 1024;
    for (int k = 0; k < 1024; ++k) s += hr[k] * Ur[k];
    const float* cr = ctx + (size_t)row * 2048;
    const float* Cr = C + (size_t)wrow * 2048;
    for (int k = 0; k < 2048; ++k) s += cr[k] * Cr[k];
    g[gg] = s;
  }
  float i_ = fast_sigm(g[0]), f_ = fast_sigm(g[1]);
  float o_ = fast_sigm(g[2]), ch = fast_tanh(g[3]);
  float cn = i_ * ch + f_ * c0[t];
  out_c[t] = cn;
  out_h[t] = o_ * fast_tanh(cn);
}

extern "C" void kernel_launch(void* const* d_in, const int* in_sizes, int n_in,
                              void* d_out, int out_size, void* d_ws, size_t ws_size,
                              hipStream_t stream) {
  const float* y   = (const float*)d_in[0];
  const float* ctx = (const float*)d_in[1];
  const float* c0  = (const float*)d_in[2];
  const float* h0  = (const float*)d_in[3];
  const float* W   = (const float*)d_in[4];
  const float* U   = (const float*)d_in[5];
  const float* C   = (const float*)d_in[6];
  const float* b   = (const float*)d_in[7];
  float* out = (float*)d_out;
  float* out_c = out;
  float* out_h = out + (size_t)Bn * Hn;

  const size_t needX = (size_t)Bn * KT * 2;
  const size_t needW = (size_t)(4 * Hn) * KT * 2;

  if (ws_size >= needX + needW) {
    unsigned short* Xb = (unsigned short*)d_ws;
    unsigned short* Wb = (unsigned short*)((char*)d_ws + needX);
    cvt_concat_k<<<2048, 256, 0, stream>>>(y, h0, ctx, Xb, (long long)Bn * 512);
    cvt_concat_k<<<2048, 256, 0, stream>>>(W, U, C, Wb, (long long)(4 * Hn) * 512);
    (void)hipFuncSetAttribute((const void*)lstm_gemm,
                              hipFuncAttributeMaxDynamicSharedMemorySize, 131072);
    lstm_gemm<<<1024, 512, 131072, stream>>>(Xb, Wb, b, c0, out_c, out_h);
  } else {
    lstm_naive<<<(Bn * Hn + 255) / 256, 256, 0, stream>>>(y, ctx, c0, h0, W, U, C,
                                                          b, out_c, out_h);
  }
}